// Round 12
// baseline (483.868 us; speedup 1.0000x reference)
//
#include <hip/hip_runtime.h>
#include <hip/hip_bf16.h>
#include <hip/hip_fp16.h>
#include <stdint.h>

// ---------------------------------------------------------------------------
// CCRGNN r12: gnn = exact r10 155us body (r11 barrier-free wave-per-graph
// regressed: 8 waves/CU < r10's 16; LDS-latency bound either way, r7/r10
// structure is the best of three tried). GEMM2 split-K x5 (fp16 partials,
// 42MB fits the 61.3MB dead fA+W1T region; 5 blocks/CU vs 4). gemm3 sums 5
// partials. conv_all + GEMM1 unchanged (GEMM1 141us ~ 990TF plateau).
// ---------------------------------------------------------------------------

typedef float f32x4 __attribute__((ext_vector_type(4)));
typedef short bf16x8 __attribute__((ext_vector_type(8)));
typedef _Float16 f16x8 __attribute__((ext_vector_type(8)));

// monotone float<->uint encoding for atomicMax on floats
__device__ __forceinline__ unsigned fenc(float f) {
  int s = __float_as_int(f);
  return s < 0 ? ~(unsigned)s : ((unsigned)s | 0x80000000u);
}
__device__ __forceinline__ float fdec(unsigned u) {
  return (u & 0x80000000u) ? __int_as_float((int)(u & 0x7fffffffu))
                           : __int_as_float(~(int)u);
}

// =================== block-per-graph GNN (2 waves, 128 thr; r7/r10 exact) ==

__global__ __launch_bounds__(128) void gnn_block(
    const float* __restrict__ x,
    const int* __restrict__ esrc, const int* __restrict__ edst,
    const float* __restrict__ W1, const float* __restrict__ a1s, const float* __restrict__ a1d, const float* __restrict__ b1,
    const float* __restrict__ W2, const float* __restrict__ a2s, const float* __restrict__ a2d, const float* __restrict__ b2,
    const float* __restrict__ W3, const float* __restrict__ a3s, const float* __restrict__ a3d, const float* __restrict__ b3,
    __hip_bfloat16* __restrict__ fA)         // tiled [4096,3328] KT=52
{
  __shared__ __align__(16) float A[1720];       // dense attention, stride 44
  __shared__ __align__(16) __half Hh2[2816];    // Ht2/h2, stride 72
  __shared__ __align__(16) __half h1h[320];     // h1, stride 8
  __shared__ __align__(16) float HfT[400];      // Ht3^T [9][44]
  __shared__ __align__(16) float sW3T[616];     // W3^T [9][68]
  __shared__ __align__(16) float xbuf[40];
  __shared__ __align__(16) float a2buf[128];    // a2s | a2d
  __shared__ float sarr[40], darr[40], den[40];
  __shared__ unsigned umax[40];
  __shared__ unsigned umx[132];                 // out0 | m1[8] | m2[64] | m3[9]
  __shared__ float a3sb[12], a3db[12], b3b[12];

  const int tid = threadIdx.x, g = blockIdx.x, w = tid >> 6, f = tid & 63;

  const int rt = g >> 7, mi = (g >> 4) & 7, lrow = g & 15;
  const size_t gbase = (size_t)rt * 52 * 8192 + (size_t)(mi * 2) * 512 + (size_t)lrow * 8;
#define COLADDR(c) (gbase + (size_t)((c) >> 6) * 8192 + (size_t)(((c) >> 5) & 1) * 512 \
                    + (size_t)(((c) >> 3) & 3) * 128 + ((c) & 7))

  // ---- setup ----
  for (int i = tid; i < 576; i += 128) { int k = i / 9, f3 = i - 9 * k; sW3T[f3 * 68 + k] = W3[i]; }
  a2buf[tid] = (tid < 64) ? a2s[tid] : a2d[tid - 64];
  if (tid < 9) { a3sb[tid] = a3s[tid]; a3db[tid] = a3d[tid]; b3b[tid] = b3[tid]; }
  for (int i = tid; i < 132; i += 128) umx[i] = 0u;
  for (int i = tid; i < 430; i += 128) *(f32x4*)&A[i * 4] = (f32x4){0.f, 0.f, 0.f, 0.f};
  for (int i = tid; i < 400; i += 128) HfT[i] = 0.f;
  if (tid < 40) { den[tid] = 0.f; umax[tid] = 0u; xbuf[tid] = 0.f; }

  float xv = 0.f;
  if (tid < 39) { xv = x[g * 39 + tid]; xbuf[tid] = xv; fA[COLADDR(tid)] = __float2bfloat16(xv); }

  int els[3], eld[3];
  const int eb = g * 312, nb0 = g * 39;
#pragma unroll
  for (int it = 0; it < 3; ++it) {
    int e = it * 128 + tid, ls = -1, ld = 0;
    if (e < 351) {
      if (e < 312) { ls = esrc[eb + e] - nb0; ld = edst[eb + e] - nb0; }
      else         { ls = e - 312; ld = ls; }
    }
    els[it] = ls; eld[it] = ld;
  }
  float c_s = 0.f, c_d = 0.f;
  const float w1r = W1[tid & 7], b1r = b1[tid & 7];
#pragma unroll
  for (int ff = 0; ff < 8; ++ff) { float wv = W1[ff]; c_s += wv * a1s[ff]; c_d += wv * a1d[ff]; }
  __syncthreads();

  // ================== layer 1 (Fin=1, Fout=8) ==================
  if (tid < 39) atomicMax(&umx[0], fenc(xv));
  float ee[3];
#pragma unroll
  for (int it = 0; it < 3; ++it) {
    if (els[it] >= 0) {
      float e = xbuf[els[it]] * c_s + xbuf[eld[it]] * c_d;
      e = (e > 0.f) ? e : 0.2f * e;
      ee[it] = e;
      atomicMax(&umax[eld[it]], fenc(e));
    }
  }
  __syncthreads();
#pragma unroll
  for (int it = 0; it < 3; ++it) {
    if (els[it] >= 0) {
      float wv = __expf(ee[it] - fdec(umax[eld[it]]));
      atomicAdd(&den[eld[it]], wv);
      atomicAdd(&A[eld[it] * 44 + els[it]], wv);
    }
  }
  __syncthreads();
  if (tid < 39) {                                      // q_i = (A x)_i / den_i
    const float* Ar = &A[tid * 44];
    float q = 0.f;
#pragma unroll
    for (int c = 0; c < 10; ++c) {
      f32x4 a4 = *(const f32x4*)&Ar[c * 4];
      f32x4 x4 = *(const f32x4*)&xbuf[c * 4];
      q += a4.x * x4.x + a4.y * x4.y + a4.z * x4.z + a4.w * x4.w;
    }
    sarr[tid] = q * (1.f / (den[tid] + 1e-16f));
  }
  __syncthreads();
#pragma unroll
  for (int it = 0; it < 3; ++it) {                     // h1 = relu(q W1 + b1)
    int slot = it * 128 + tid;
    if (slot < 312) {
      int i = slot >> 3, fi = slot & 7;
      float v = fmaxf(sarr[i] * w1r + b1r, 0.f);
      h1h[slot] = __float2half(v);
      fA[COLADDR(39 + slot)] = __float2bfloat16(v);
      atomicMax(&umx[1 + fi], fenc(v));
    }
  }
  __syncthreads();

  // ================== layer 2 (Fin=8, Fout=64) ==================
  float ht2r[40];                                      // register Ht2 column (lane=f)
  {
    float w2k[8];
#pragma unroll
    for (int k = 0; k < 8; ++k) w2k[k] = W2[k * 64 + f];
#pragma unroll
    for (int i = 0; i < 39; ++i) {
      f16x8 hr = *(const f16x8*)&h1h[i * 8];
      float hv = 0.f;
#pragma unroll
      for (int k = 0; k < 8; ++k) hv += (float)hr[k] * w2k[k];
      ht2r[i] = hv;
    }
    ht2r[39] = 0.f;
#pragma unroll
    for (int i = 0; i < 39; ++i) {
      if ((i < 20) ? (w == 0) : (w == 1))
        Hh2[i * 72 + f] = __float2half(ht2r[i]);
    }
    for (int i = tid; i < 430; i += 128) *(f32x4*)&A[i * 4] = (f32x4){0.f, 0.f, 0.f, 0.f};
    if (tid < 39) { den[tid] = 0.f; umax[tid] = 0u; }
  }
  __syncthreads();
  {                                                    // s (wave0), d (wave1)
    int node = f;
    if (node < 39) {
      const float* ab = a2buf + (tid & 64);
      const __half* hr = &Hh2[node * 72];
      float s = 0.f;
#pragma unroll
      for (int c = 0; c < 8; ++c) {
        f16x8 hv = *(const f16x8*)&hr[c * 8];
        f32x4 a0 = *(const f32x4*)&ab[c * 8];
        f32x4 a1 = *(const f32x4*)&ab[c * 8 + 4];
        s += (float)hv[0] * a0.x + (float)hv[1] * a0.y + (float)hv[2] * a0.z + (float)hv[3] * a0.w
           + (float)hv[4] * a1.x + (float)hv[5] * a1.y + (float)hv[6] * a1.z + (float)hv[7] * a1.w;
      }
      if (tid < 64) sarr[node] = s; else darr[node] = s;
    }
  }
  __syncthreads();
#pragma unroll
  for (int it = 0; it < 3; ++it) {
    if (els[it] >= 0) {
      float e = sarr[els[it]] + darr[eld[it]];
      e = (e > 0.f) ? e : 0.2f * e;
      ee[it] = e;
      atomicMax(&umax[eld[it]], fenc(e));
    }
  }
  __syncthreads();
#pragma unroll
  for (int it = 0; it < 3; ++it) {
    if (els[it] >= 0) {
      float wv = __expf(ee[it] - fdec(umax[eld[it]]));
      atomicAdd(&den[eld[it]], wv);
      atomicAdd(&A[eld[it] * 44 + els[it]], wv);
    }
  }
  __syncthreads();
  {                                                    // h2 = relu(A ht2r / den + b2)
    const float b2r = b2[f];
    for (int it = 0; it < 20; ++it) {
      int i = it * 2 + w;
      if (i < 39) {
        float inv = 1.f / (den[i] + 1e-16f);
        const float* Ar = &A[i * 44];
        float acc = 0.f;
#pragma unroll
        for (int c = 0; c < 10; ++c) {
          f32x4 a4 = *(const f32x4*)&Ar[c * 4];
          acc += a4.x * ht2r[c * 4] + a4.y * ht2r[c * 4 + 1]
               + a4.z * ht2r[c * 4 + 2] + a4.w * ht2r[c * 4 + 3];
        }
        float v = fmaxf(acc * inv + b2r, 0.f);
        Hh2[i * 72 + f] = __float2half(v);
        fA[COLADDR(351 + i * 64 + f)] = __float2bfloat16(v);
        atomicMax(&umx[9 + f], fenc(v));
      }
    }
  }
  __syncthreads();

  // ================== layer 3 (Fin=64, Fout=9) ==================
  {
#pragma unroll
    for (int it = 0; it < 3; ++it) {                   // Ht3^T = (h2 @ W3)^T
      int slot = it * 128 + tid;
      if (slot < 351) {
        int i = slot / 9, f3 = slot - 9 * i;
        const __half* hr = &Hh2[i * 72];
        const float* wr = &sW3T[f3 * 68];
        float acc = 0.f;
#pragma unroll
        for (int c = 0; c < 8; ++c) {
          f16x8 hv = *(const f16x8*)&hr[c * 8];
          f32x4 w0 = *(const f32x4*)&wr[c * 8];
          f32x4 w1 = *(const f32x4*)&wr[c * 8 + 4];
          acc += (float)hv[0] * w0.x + (float)hv[1] * w0.y + (float)hv[2] * w0.z + (float)hv[3] * w0.w
               + (float)hv[4] * w1.x + (float)hv[5] * w1.y + (float)hv[6] * w1.z + (float)hv[7] * w1.w;
        }
        HfT[f3 * 44 + i] = acc;
      }
    }
    for (int i = tid; i < 430; i += 128) *(f32x4*)&A[i * 4] = (f32x4){0.f, 0.f, 0.f, 0.f};
    if (tid < 39) { den[tid] = 0.f; umax[tid] = 0u; }
  }
  __syncthreads();
  {
    int node = f;
    if (node < 39) {
      const float* av = (tid < 64) ? a3sb : a3db;
      float s = 0.f;
#pragma unroll
      for (int f3 = 0; f3 < 9; ++f3) s += HfT[f3 * 44 + node] * av[f3];
      if (tid < 64) sarr[node] = s; else darr[node] = s;
    }
  }
  __syncthreads();
#pragma unroll
  for (int it = 0; it < 3; ++it) {
    if (els[it] >= 0) {
      float e = sarr[els[it]] + darr[eld[it]];
      e = (e > 0.f) ? e : 0.2f * e;
      ee[it] = e;
      atomicMax(&umax[eld[it]], fenc(e));
    }
  }
  __syncthreads();
#pragma unroll
  for (int it = 0; it < 3; ++it) {
    if (els[it] >= 0) {
      float wv = __expf(ee[it] - fdec(umax[eld[it]]));
      atomicAdd(&den[eld[it]], wv);
      atomicAdd(&A[eld[it] * 44 + els[it]], wv);
    }
  }
  __syncthreads();
#pragma unroll
  for (int it = 0; it < 3; ++it) {                     // h3 = relu(A Ht3 / den + b3)
    int slot = it * 128 + tid;
    if (slot < 351) {
      int i = slot / 9, f3 = slot - 9 * i;
      float inv = 1.f / (den[i] + 1e-16f);
      const float* Ar = &A[i * 44];
      const float* Hr = &HfT[f3 * 44];
      float acc = 0.f;
#pragma unroll
      for (int c = 0; c < 10; ++c) {
        f32x4 a4 = *(const f32x4*)&Ar[c * 4];
        f32x4 h4 = *(const f32x4*)&Hr[c * 4];
        acc += a4.x * h4.x + a4.y * h4.y + a4.z * h4.z + a4.w * h4.w;
      }
      float v = fmaxf(acc * inv + b3b[f3], 0.f);
      fA[COLADDR(2847 + slot)] = __float2bfloat16(v);
      atomicMax(&umx[73 + f3], fenc(v));
    }
  }
  __syncthreads();

  // ---- segment maxes + pad (cols 3198..3327) ----
  if (tid < 130) {
    int c = 3198 + tid;
    float v = (tid < 82) ? fdec(umx[tid]) : 0.f;
    fA[COLADDR(c)] = __float2bfloat16(v);
  }
#undef COLADDR
}

// ===== merged weight transposes: fp32 [K0,N0] -> bf16 fragment-tiled =======
// Homogeneous grid: blocks 0..4159 -> W1T (52x80 tiles), 4160..5439 -> W2T.

__global__ __launch_bounds__(256) void conv_all(
    const float* __restrict__ lW1, const float* __restrict__ lW2,
    short* __restrict__ W1T, short* __restrict__ W2T)
{
  __shared__ float t[64][68];
  const int bid = blockIdx.x, tid = threadIdx.x;
  const float* W; short* WT; int ktile, ntile, K0, N0, KT;
  if (bid < 4160) { W = lW1; WT = W1T; ktile = bid % 52; ntile = bid / 52; K0 = 3280; N0 = 5000; KT = 52; }
  else { int c2 = bid - 4160; W = lW2; WT = W2T; ktile = c2 % 80; ntile = c2 / 80; K0 = 5000; N0 = 1024; KT = 80; }

  const int kb = ktile * 64, nb = ntile * 64;
  const int tx = tid & 15, ty = tid >> 4;
#pragma unroll
  for (int r = 0; r < 4; ++r) {
    int k = kb + ty + r * 16, n = nb + tx * 4;
    float4 v = make_float4(0.f, 0.f, 0.f, 0.f);
    if (k < K0 && n < N0) v = *(const float4*)&W[(size_t)k * N0 + n];   // N0 % 4 == 0
    t[ty + r * 16][tx * 4 + 0] = v.x; t[ty + r * 16][tx * 4 + 1] = v.y;
    t[ty + r * 16][tx * 4 + 2] = v.z; t[ty + r * 16][tx * 4 + 3] = v.w;
  }
  __syncthreads();
  const int nl = tid >> 2, kc0 = tid & 3;
#pragma unroll
  for (int h = 0; h < 2; ++h) {
    int kc = kc0 + h * 4;
    int n = nb + nl, k = kb + kc * 8;
    union { bf16x8 v; __hip_bfloat16 b[8]; } z;
#pragma unroll
    for (int j = 0; j < 8; ++j) z.b[j] = __float2bfloat16(t[kc * 8 + j][nl]);
    int rt = n >> 7, mi = (n >> 4) & 7, lr = n & 15;
    int kt = k >> 6, kq = (k >> 5) & 1, lc = (k >> 3) & 3;
    size_t addr = ((((size_t)rt * KT) + kt) * 16 + mi * 2 + kq) * 512 + ((size_t)lr + 16 * lc) * 8;
    *(bf16x8*)&WT[addr] = z.v;
  }
}

// ======================= tiled bf16 MFMA GEMM ==============================

__device__ __forceinline__ void gld_lds16(const void* gptr, void* l) {
  typedef const __attribute__((address_space(1))) unsigned int GU;
  typedef __attribute__((address_space(3))) unsigned int LU;
  __builtin_amdgcn_global_load_lds((GU*)gptr, (LU*)l, 16, 0, 0);
}

// MODE 0: C tiled bf16 (next GEMM's A, outKT = Nn/64), +bias +relu
// MODE 1: fp16 partials P[splits][4096][Nn] row-major
template<int MODE>
__global__ __launch_bounds__(256) void gemm_tiled(
    const short* __restrict__ A, const short* __restrict__ B,
    const float* __restrict__ bias, int Nreal,
    void* __restrict__ Cout, int Nn, int KT, int ktPerSplit, int outKT)
{
  __shared__ __align__(16) short lA[8192];
  __shared__ __align__(16) short lB[8192];
  const int tid = threadIdx.x;
  const int w = tid >> 6, L = tid & 63;
  const int lrow = L & 15, lch = L >> 4;
  const int mt = blockIdx.y, nt = blockIdx.x;
  const int mw = (w >> 1) * 4, nw = (w & 1) * 4;
  const int kt0 = blockIdx.z * ktPerSplit, kt1 = kt0 + ktPerSplit;

  const short* Ab = A + ((size_t)mt * KT) * 8192 + (size_t)L * 8;
  const short* Bb = B + ((size_t)nt * KT) * 8192 + (size_t)L * 8;

  f32x4 acc[4][4] = {};

  for (int kt = kt0; kt < kt1; ++kt) {
    const short* Ak = Ab + (size_t)kt * 8192;
    const short* Bk = Bb + (size_t)kt * 8192;
#pragma unroll
    for (int j = 0; j < 4; ++j) {
      int st = w * 4 + j;
      gld_lds16(Ak + st * 512, &lA[st * 512]);
      gld_lds16(Bk + st * 512, &lB[st * 512]);
    }
    __syncthreads();
#pragma unroll
    for (int kk = 0; kk < 2; ++kk) {
      bf16x8 af[4], bfr[4];
#pragma unroll
      for (int i = 0; i < 4; ++i) {
        af[i]  = *(const bf16x8*)&lA[((mw + i) * 2 + kk) * 512 + L * 8];
        bfr[i] = *(const bf16x8*)&lB[((nw + i) * 2 + kk) * 512 + L * 8];
      }
#pragma unroll
      for (int i = 0; i < 4; ++i)
#pragma unroll
        for (int j = 0; j < 4; ++j)
          acc[i][j] = __builtin_amdgcn_mfma_f32_16x16x32_bf16(af[i], bfr[j], acc[i][j], 0, 0, 0);
    }
    __syncthreads();
  }

  if (MODE == 0) {
    __hip_bfloat16* C = (__hip_bfloat16*)Cout;
#pragma unroll
    for (int j = 0; j < 4; ++j) {
      int n = nt * 128 + (nw + j) * 16 + lrow;
      float bn = (n < Nreal) ? bias[n] : 0.f;
      int kt = n >> 6, kq = (n >> 5) & 1, lc2 = (n >> 3) & 3, j2 = n & 7;
#pragma unroll
      for (int i = 0; i < 4; ++i) {
        int mi = mw + i;
        size_t base = ((((size_t)mt * outKT + kt) * 16) + mi * 2 + kq) * 512
                      + (size_t)(lch * 4) * 8 + (size_t)lc2 * 128 + j2;
#pragma unroll
        for (int r = 0; r < 4; ++r)
          C[base + r * 8] = __float2bfloat16(fmaxf(acc[i][j][r] + bn, 0.f));
      }
    }
  } else {
    __half* P = (__half*)Cout + (size_t)blockIdx.z * 4096 * 1024;
#pragma unroll
    for (int j = 0; j < 4; ++j) {
      int n = nt * 128 + (nw + j) * 16 + lrow;
#pragma unroll
      for (int i = 0; i < 4; ++i)
#pragma unroll
        for (int r = 0; r < 4; ++r) {
          int m = mt * 128 + (mw + i) * 16 + lch * 4 + r;
          P[(size_t)m * Nn + n] = __float2half(acc[i][j][r]);
        }
    }
  }
}

// == final: relu(sum P0..P4 + b2) @ W3 + b3 -> fp32 out (reduce fused) ======

__global__ __launch_bounds__(256) void gemm3_fused(
    const __half* __restrict__ P,     // [5][4096][1024] fp16
    const float* __restrict__ b2v,    // lb2 [1024]
    const float* __restrict__ W3,     // lW3 [1024,9]
    const float* __restrict__ b3v,    // lb3 [9]
    float* __restrict__ out)          // [4096,9]
{
  __shared__ float sW3[9 * 1024];
  int tid = threadIdx.x;
  for (int i = tid; i < 9216; i += 256) { int k = i / 9, j = i - 9 * k; sW3[j * 1024 + k] = W3[i]; }
  __syncthreads();
  int row = blockIdx.x * 4 + (tid >> 6);
  int lane = tid & 63;
  const __half* p0 = P + (size_t)row * 1024;
  const size_t S = (size_t)4096 * 1024;
  float acc[9] = {0, 0, 0, 0, 0, 0, 0, 0, 0};
  for (int t = 0; t < 16; ++t) {
    int k = lane + 64 * t;
    float c = __half2float(p0[k]) + __half2float(p0[k + S])
            + __half2float(p0[k + 2 * S]) + __half2float(p0[k + 3 * S])
            + __half2float(p0[k + 4 * S]) + b2v[k];
    c = fmaxf(c, 0.f);
#pragma unroll
    for (int j = 0; j < 9; ++j) acc[j] += c * sW3[j * 1024 + k];
  }
#pragma unroll
  for (int j = 0; j < 9; ++j) {
    float v = acc[j];
    v += __shfl_down(v, 32, 64);
    v += __shfl_down(v, 16, 64);
    v += __shfl_down(v, 8, 64);
    v += __shfl_down(v, 4, 64);
    v += __shfl_down(v, 2, 64);
    v += __shfl_down(v, 1, 64);
    if (lane == 0) out[(size_t)row * 9 + j] = v + b3v[j];
  }
}

// ============================= launch =======================================

extern "C" void kernel_launch(void* const* d_in, const int* in_sizes, int n_in,
                              void* d_out, int out_size, void* d_ws, size_t ws_size,
                              hipStream_t stream)
{
  const float* x   = (const float*)d_in[0];
  const int*   ei  = (const int*)d_in[1];
  const float* W1  = (const float*)d_in[3];
  const float* a1s = (const float*)d_in[4];
  const float* a1d = (const float*)d_in[5];
  const float* b1  = (const float*)d_in[6];
  const float* W2  = (const float*)d_in[7];
  const float* a2s = (const float*)d_in[8];
  const float* a2d = (const float*)d_in[9];
  const float* b2  = (const float*)d_in[10];
  const float* W3  = (const float*)d_in[11];
  const float* a3s = (const float*)d_in[12];
  const float* a3d = (const float*)d_in[13];
  const float* b3  = (const float*)d_in[14];
  const float* lW1 = (const float*)d_in[15];
  const float* lb1 = (const float*)d_in[16];
  const float* lW2 = (const float*)d_in[17];
  const float* lb2 = (const float*)d_in[18];
  const float* lW3 = (const float*)d_in[19];
  const float* lb3 = (const float*)d_in[20];

  const int E = 4096 * 39 * 8;
  const int* esrc = ei;
  const int* edst = ei + E;

  // ws (bf16 elems): fA 13.6M | W1T 17.0M | C1 21.0M | W2T 5.2M  (~114 MB)
  short* fA  = (short*)d_ws;                       // tiled [4096,3328] KT=52
  short* W1T = fA  + (size_t)4096 * 3328;          // tiled [5120,3328] KT=52
  short* C1  = W1T + (size_t)5120 * 3328;          // tiled [4096,5120] KT=80
  short* W2T = C1  + (size_t)4096 * 5120;          // tiled [1024,5120] KT=80
  __half* P  = (__half*)d_ws;                      // 5x[4096,1024] fp16 (42MB), aliases fA+W1T (dead)

  conv_all<<<5440, 256, 0, stream>>>(lW1, lW2, W1T, W2T);
  gnn_block<<<4096, 128, 0, stream>>>(x, esrc, edst,
                                      W1, a1s, a1d, b1, W2, a2s, a2d, b2, W3, a3s, a3d, b3,
                                      (__hip_bfloat16*)fA);
  gemm_tiled<0><<<dim3(40, 32, 1), 256, 0, stream>>>(fA, W1T, lb1, 5000, C1, 5120, 52, 52, 80);
  gemm_tiled<1><<<dim3(8, 32, 5), 256, 0, stream>>>(C1, W2T, nullptr, 1024, P, 1024, 80, 16, 0);
  gemm3_fused<<<1024, 256, 0, stream>>>(P, lb2, lW3, lb3, (float*)d_out);
}

// Round 13
// 471.827 us; speedup vs baseline: 1.0255x; 1.0255x over previous
//
#include <hip/hip_runtime.h>
#include <hip/hip_bf16.h>
#include <hip/hip_fp16.h>
#include <stdint.h>

// ---------------------------------------------------------------------------
// CCRGNN r13: best-known config locked: gnn = r10 155us body; GEMM1 = 990TF
// fragment-tiled (HIP plateau); GEMM2 = split-K x4 fp16 partials (best of
// x2/x4/x5, all ~equal); gemm3 sums 4 partials. NEW: conv_all re-tiled to
// 16k x 256n so every wave load is one contiguous 1KiB segment (was 4x256B),
// LDS stride 260 -> only 2-way bank aliasing (free, m136).
// ---------------------------------------------------------------------------

typedef float f32x4 __attribute__((ext_vector_type(4)));
typedef short bf16x8 __attribute__((ext_vector_type(8)));
typedef _Float16 f16x8 __attribute__((ext_vector_type(8)));

// monotone float<->uint encoding for atomicMax on floats
__device__ __forceinline__ unsigned fenc(float f) {
  int s = __float_as_int(f);
  return s < 0 ? ~(unsigned)s : ((unsigned)s | 0x80000000u);
}
__device__ __forceinline__ float fdec(unsigned u) {
  return (u & 0x80000000u) ? __int_as_float((int)(u & 0x7fffffffu))
                           : __int_as_float(~(int)u);
}

// =================== block-per-graph GNN (2 waves, 128 thr; r10 exact) =====

__global__ __launch_bounds__(128) void gnn_block(
    const float* __restrict__ x,
    const int* __restrict__ esrc, const int* __restrict__ edst,
    const float* __restrict__ W1, const float* __restrict__ a1s, const float* __restrict__ a1d, const float* __restrict__ b1,
    const float* __restrict__ W2, const float* __restrict__ a2s, const float* __restrict__ a2d, const float* __restrict__ b2,
    const float* __restrict__ W3, const float* __restrict__ a3s, const float* __restrict__ a3d, const float* __restrict__ b3,
    __hip_bfloat16* __restrict__ fA)         // tiled [4096,3328] KT=52
{
  __shared__ __align__(16) float A[1720];       // dense attention, stride 44
  __shared__ __align__(16) __half Hh2[2816];    // Ht2/h2, stride 72
  __shared__ __align__(16) __half h1h[320];     // h1, stride 8
  __shared__ __align__(16) float HfT[400];      // Ht3^T [9][44]
  __shared__ __align__(16) float sW3T[616];     // W3^T [9][68]
  __shared__ __align__(16) float xbuf[40];
  __shared__ __align__(16) float a2buf[128];    // a2s | a2d
  __shared__ float sarr[40], darr[40], den[40];
  __shared__ unsigned umax[40];
  __shared__ unsigned umx[132];                 // out0 | m1[8] | m2[64] | m3[9]
  __shared__ float a3sb[12], a3db[12], b3b[12];

  const int tid = threadIdx.x, g = blockIdx.x, w = tid >> 6, f = tid & 63;

  const int rt = g >> 7, mi = (g >> 4) & 7, lrow = g & 15;
  const size_t gbase = (size_t)rt * 52 * 8192 + (size_t)(mi * 2) * 512 + (size_t)lrow * 8;
#define COLADDR(c) (gbase + (size_t)((c) >> 6) * 8192 + (size_t)(((c) >> 5) & 1) * 512 \
                    + (size_t)(((c) >> 3) & 3) * 128 + ((c) & 7))

  // ---- setup ----
  for (int i = tid; i < 576; i += 128) { int k = i / 9, f3 = i - 9 * k; sW3T[f3 * 68 + k] = W3[i]; }
  a2buf[tid] = (tid < 64) ? a2s[tid] : a2d[tid - 64];
  if (tid < 9) { a3sb[tid] = a3s[tid]; a3db[tid] = a3d[tid]; b3b[tid] = b3[tid]; }
  for (int i = tid; i < 132; i += 128) umx[i] = 0u;
  for (int i = tid; i < 430; i += 128) *(f32x4*)&A[i * 4] = (f32x4){0.f, 0.f, 0.f, 0.f};
  for (int i = tid; i < 400; i += 128) HfT[i] = 0.f;
  if (tid < 40) { den[tid] = 0.f; umax[tid] = 0u; xbuf[tid] = 0.f; }

  float xv = 0.f;
  if (tid < 39) { xv = x[g * 39 + tid]; xbuf[tid] = xv; fA[COLADDR(tid)] = __float2bfloat16(xv); }

  int els[3], eld[3];
  const int eb = g * 312, nb0 = g * 39;
#pragma unroll
  for (int it = 0; it < 3; ++it) {
    int e = it * 128 + tid, ls = -1, ld = 0;
    if (e < 351) {
      if (e < 312) { ls = esrc[eb + e] - nb0; ld = edst[eb + e] - nb0; }
      else         { ls = e - 312; ld = ls; }
    }
    els[it] = ls; eld[it] = ld;
  }
  float c_s = 0.f, c_d = 0.f;
  const float w1r = W1[tid & 7], b1r = b1[tid & 7];
#pragma unroll
  for (int ff = 0; ff < 8; ++ff) { float wv = W1[ff]; c_s += wv * a1s[ff]; c_d += wv * a1d[ff]; }
  __syncthreads();

  // ================== layer 1 (Fin=1, Fout=8) ==================
  if (tid < 39) atomicMax(&umx[0], fenc(xv));
  float ee[3];
#pragma unroll
  for (int it = 0; it < 3; ++it) {
    if (els[it] >= 0) {
      float e = xbuf[els[it]] * c_s + xbuf[eld[it]] * c_d;
      e = (e > 0.f) ? e : 0.2f * e;
      ee[it] = e;
      atomicMax(&umax[eld[it]], fenc(e));
    }
  }
  __syncthreads();
#pragma unroll
  for (int it = 0; it < 3; ++it) {
    if (els[it] >= 0) {
      float wv = __expf(ee[it] - fdec(umax[eld[it]]));
      atomicAdd(&den[eld[it]], wv);
      atomicAdd(&A[eld[it] * 44 + els[it]], wv);
    }
  }
  __syncthreads();
  if (tid < 39) {                                      // q_i = (A x)_i / den_i
    const float* Ar = &A[tid * 44];
    float q = 0.f;
#pragma unroll
    for (int c = 0; c < 10; ++c) {
      f32x4 a4 = *(const f32x4*)&Ar[c * 4];
      f32x4 x4 = *(const f32x4*)&xbuf[c * 4];
      q += a4.x * x4.x + a4.y * x4.y + a4.z * x4.z + a4.w * x4.w;
    }
    sarr[tid] = q * (1.f / (den[tid] + 1e-16f));
  }
  __syncthreads();
#pragma unroll
  for (int it = 0; it < 3; ++it) {                     // h1 = relu(q W1 + b1)
    int slot = it * 128 + tid;
    if (slot < 312) {
      int i = slot >> 3, fi = slot & 7;
      float v = fmaxf(sarr[i] * w1r + b1r, 0.f);
      h1h[slot] = __float2half(v);
      fA[COLADDR(39 + slot)] = __float2bfloat16(v);
      atomicMax(&umx[1 + fi], fenc(v));
    }
  }
  __syncthreads();

  // ================== layer 2 (Fin=8, Fout=64) ==================
  float ht2r[40];                                      // register Ht2 column (lane=f)
  {
    float w2k[8];
#pragma unroll
    for (int k = 0; k < 8; ++k) w2k[k] = W2[k * 64 + f];
#pragma unroll
    for (int i = 0; i < 39; ++i) {
      f16x8 hr = *(const f16x8*)&h1h[i * 8];
      float hv = 0.f;
#pragma unroll
      for (int k = 0; k < 8; ++k) hv += (float)hr[k] * w2k[k];
      ht2r[i] = hv;
    }
    ht2r[39] = 0.f;
#pragma unroll
    for (int i = 0; i < 39; ++i) {
      if ((i < 20) ? (w == 0) : (w == 1))
        Hh2[i * 72 + f] = __float2half(ht2r[i]);
    }
    for (int i = tid; i < 430; i += 128) *(f32x4*)&A[i * 4] = (f32x4){0.f, 0.f, 0.f, 0.f};
    if (tid < 39) { den[tid] = 0.f; umax[tid] = 0u; }
  }
  __syncthreads();
  {                                                    // s (wave0), d (wave1)
    int node = f;
    if (node < 39) {
      const float* ab = a2buf + (tid & 64);
      const __half* hr = &Hh2[node * 72];
      float s = 0.f;
#pragma unroll
      for (int c = 0; c < 8; ++c) {
        f16x8 hv = *(const f16x8*)&hr[c * 8];
        f32x4 a0 = *(const f32x4*)&ab[c * 8];
        f32x4 a1 = *(const f32x4*)&ab[c * 8 + 4];
        s += (float)hv[0] * a0.x + (float)hv[1] * a0.y + (float)hv[2] * a0.z + (float)hv[3] * a0.w
           + (float)hv[4] * a1.x + (float)hv[5] * a1.y + (float)hv[6] * a1.z + (float)hv[7] * a1.w;
      }
      if (tid < 64) sarr[node] = s; else darr[node] = s;
    }
  }
  __syncthreads();
#pragma unroll
  for (int it = 0; it < 3; ++it) {
    if (els[it] >= 0) {
      float e = sarr[els[it]] + darr[eld[it]];
      e = (e > 0.f) ? e : 0.2f * e;
      ee[it] = e;
      atomicMax(&umax[eld[it]], fenc(e));
    }
  }
  __syncthreads();
#pragma unroll
  for (int it = 0; it < 3; ++it) {
    if (els[it] >= 0) {
      float wv = __expf(ee[it] - fdec(umax[eld[it]]));
      atomicAdd(&den[eld[it]], wv);
      atomicAdd(&A[eld[it] * 44 + els[it]], wv);
    }
  }
  __syncthreads();
  {                                                    // h2 = relu(A ht2r / den + b2)
    const float b2r = b2[f];
    for (int it = 0; it < 20; ++it) {
      int i = it * 2 + w;
      if (i < 39) {
        float inv = 1.f / (den[i] + 1e-16f);
        const float* Ar = &A[i * 44];
        float acc = 0.f;
#pragma unroll
        for (int c = 0; c < 10; ++c) {
          f32x4 a4 = *(const f32x4*)&Ar[c * 4];
          acc += a4.x * ht2r[c * 4] + a4.y * ht2r[c * 4 + 1]
               + a4.z * ht2r[c * 4 + 2] + a4.w * ht2r[c * 4 + 3];
        }
        float v = fmaxf(acc * inv + b2r, 0.f);
        Hh2[i * 72 + f] = __float2half(v);
        fA[COLADDR(351 + i * 64 + f)] = __float2bfloat16(v);
        atomicMax(&umx[9 + f], fenc(v));
      }
    }
  }
  __syncthreads();

  // ================== layer 3 (Fin=64, Fout=9) ==================
  {
#pragma unroll
    for (int it = 0; it < 3; ++it) {                   // Ht3^T = (h2 @ W3)^T
      int slot = it * 128 + tid;
      if (slot < 351) {
        int i = slot / 9, f3 = slot - 9 * i;
        const __half* hr = &Hh2[i * 72];
        const float* wr = &sW3T[f3 * 68];
        float acc = 0.f;
#pragma unroll
        for (int c = 0; c < 8; ++c) {
          f16x8 hv = *(const f16x8*)&hr[c * 8];
          f32x4 w0 = *(const f32x4*)&wr[c * 8];
          f32x4 w1 = *(const f32x4*)&wr[c * 8 + 4];
          acc += (float)hv[0] * w0.x + (float)hv[1] * w0.y + (float)hv[2] * w0.z + (float)hv[3] * w0.w
               + (float)hv[4] * w1.x + (float)hv[5] * w1.y + (float)hv[6] * w1.z + (float)hv[7] * w1.w;
        }
        HfT[f3 * 44 + i] = acc;
      }
    }
    for (int i = tid; i < 430; i += 128) *(f32x4*)&A[i * 4] = (f32x4){0.f, 0.f, 0.f, 0.f};
    if (tid < 39) { den[tid] = 0.f; umax[tid] = 0u; }
  }
  __syncthreads();
  {
    int node = f;
    if (node < 39) {
      const float* av = (tid < 64) ? a3sb : a3db;
      float s = 0.f;
#pragma unroll
      for (int f3 = 0; f3 < 9; ++f3) s += HfT[f3 * 44 + node] * av[f3];
      if (tid < 64) sarr[node] = s; else darr[node] = s;
    }
  }
  __syncthreads();
#pragma unroll
  for (int it = 0; it < 3; ++it) {
    if (els[it] >= 0) {
      float e = sarr[els[it]] + darr[eld[it]];
      e = (e > 0.f) ? e : 0.2f * e;
      ee[it] = e;
      atomicMax(&umax[eld[it]], fenc(e));
    }
  }
  __syncthreads();
#pragma unroll
  for (int it = 0; it < 3; ++it) {
    if (els[it] >= 0) {
      float wv = __expf(ee[it] - fdec(umax[eld[it]]));
      atomicAdd(&den[eld[it]], wv);
      atomicAdd(&A[eld[it] * 44 + els[it]], wv);
    }
  }
  __syncthreads();
#pragma unroll
  for (int it = 0; it < 3; ++it) {                     // h3 = relu(A Ht3 / den + b3)
    int slot = it * 128 + tid;
    if (slot < 351) {
      int i = slot / 9, f3 = slot - 9 * i;
      float inv = 1.f / (den[i] + 1e-16f);
      const float* Ar = &A[i * 44];
      const float* Hr = &HfT[f3 * 44];
      float acc = 0.f;
#pragma unroll
      for (int c = 0; c < 10; ++c) {
        f32x4 a4 = *(const f32x4*)&Ar[c * 4];
        f32x4 h4 = *(const f32x4*)&Hr[c * 4];
        acc += a4.x * h4.x + a4.y * h4.y + a4.z * h4.z + a4.w * h4.w;
      }
      float v = fmaxf(acc * inv + b3b[f3], 0.f);
      fA[COLADDR(2847 + slot)] = __float2bfloat16(v);
      atomicMax(&umx[73 + f3], fenc(v));
    }
  }
  __syncthreads();

  // ---- segment maxes + pad (cols 3198..3327) ----
  if (tid < 130) {
    int c = 3198 + tid;
    float v = (tid < 82) ? fdec(umx[tid]) : 0.f;
    fA[COLADDR(c)] = __float2bfloat16(v);
  }
#undef COLADDR
}

// ===== weight transposes: fp32 [K0,N0] -> bf16 fragment-tiled ==============
// 16k x 256n tiles: each wave-load is ONE contiguous 1KiB segment.
// Blocks 0..4159 -> W1T (208 x 20 tiles), 4160..5439 -> W2T (320 x 4).

__global__ __launch_bounds__(256) void conv_all(
    const float* __restrict__ lW1, const float* __restrict__ lW2,
    short* __restrict__ W1T, short* __restrict__ W2T)
{
  __shared__ float t[16][260];
  const int bid = blockIdx.x, tid = threadIdx.x;
  const float* W; short* WT; int ktile, ntile, K0, N0, KT;
  if (bid < 4160) { W = lW1; WT = W1T; ktile = bid % 208; ntile = bid / 208; K0 = 3280; N0 = 5000; KT = 52; }
  else { int c2 = bid - 4160; W = lW2; WT = W2T; ktile = c2 % 320; ntile = c2 / 320; K0 = 5000; N0 = 1024; KT = 80; }

  const int kb = ktile * 16, nb = ntile * 256;
  const int wv = tid >> 6, ln = tid & 63;
#pragma unroll
  for (int r = 0; r < 4; ++r) {
    int k = kb + wv * 4 + r;                  // wave wv handles rows wv*4..wv*4+3
    int n = nb + ln * 4;
    f32x4 v = (f32x4){0.f, 0.f, 0.f, 0.f};
    if (k < K0 && n < N0) v = *(const f32x4*)&W[(size_t)k * N0 + n];   // N0 % 4 == 0
    *(f32x4*)&t[wv * 4 + r][ln * 4] = v;
  }
  __syncthreads();
#pragma unroll
  for (int h = 0; h < 2; ++h) {
    int c = h * 256 + tid;                    // 512 chunks: (n_local, kc)
    int nl = c >> 1, kc = c & 1;
    int n = nb + nl, k = kb + kc * 8;
    union { bf16x8 v; __hip_bfloat16 b[8]; } z;
#pragma unroll
    for (int j = 0; j < 8; ++j) z.b[j] = __float2bfloat16(t[kc * 8 + j][nl]);
    int rt = n >> 7, mi = (n >> 4) & 7, lr = n & 15;
    int kt = k >> 6, kq = (k >> 5) & 1, lc = (k >> 3) & 3;
    size_t addr = ((((size_t)rt * KT) + kt) * 16 + mi * 2 + kq) * 512 + ((size_t)lr + 16 * lc) * 8;
    *(bf16x8*)&WT[addr] = z.v;
  }
}

// ======================= tiled bf16 MFMA GEMM ==============================

__device__ __forceinline__ void gld_lds16(const void* gptr, void* l) {
  typedef const __attribute__((address_space(1))) unsigned int GU;
  typedef __attribute__((address_space(3))) unsigned int LU;
  __builtin_amdgcn_global_load_lds((GU*)gptr, (LU*)l, 16, 0, 0);
}

// MODE 0: C tiled bf16 (next GEMM's A, outKT = Nn/64), +bias +relu
// MODE 1: fp16 partials P[splits][4096][Nn] row-major
template<int MODE>
__global__ __launch_bounds__(256) void gemm_tiled(
    const short* __restrict__ A, const short* __restrict__ B,
    const float* __restrict__ bias, int Nreal,
    void* __restrict__ Cout, int Nn, int KT, int ktPerSplit, int outKT)
{
  __shared__ __align__(16) short lA[8192];
  __shared__ __align__(16) short lB[8192];
  const int tid = threadIdx.x;
  const int w = tid >> 6, L = tid & 63;
  const int lrow = L & 15, lch = L >> 4;
  const int mt = blockIdx.y, nt = blockIdx.x;
  const int mw = (w >> 1) * 4, nw = (w & 1) * 4;
  const int kt0 = blockIdx.z * ktPerSplit, kt1 = kt0 + ktPerSplit;

  const short* Ab = A + ((size_t)mt * KT) * 8192 + (size_t)L * 8;
  const short* Bb = B + ((size_t)nt * KT) * 8192 + (size_t)L * 8;

  f32x4 acc[4][4] = {};

  for (int kt = kt0; kt < kt1; ++kt) {
    const short* Ak = Ab + (size_t)kt * 8192;
    const short* Bk = Bb + (size_t)kt * 8192;
#pragma unroll
    for (int j = 0; j < 4; ++j) {
      int st = w * 4 + j;
      gld_lds16(Ak + st * 512, &lA[st * 512]);
      gld_lds16(Bk + st * 512, &lB[st * 512]);
    }
    __syncthreads();
#pragma unroll
    for (int kk = 0; kk < 2; ++kk) {
      bf16x8 af[4], bfr[4];
#pragma unroll
      for (int i = 0; i < 4; ++i) {
        af[i]  = *(const bf16x8*)&lA[((mw + i) * 2 + kk) * 512 + L * 8];
        bfr[i] = *(const bf16x8*)&lB[((nw + i) * 2 + kk) * 512 + L * 8];
      }
#pragma unroll
      for (int i = 0; i < 4; ++i)
#pragma unroll
        for (int j = 0; j < 4; ++j)
          acc[i][j] = __builtin_amdgcn_mfma_f32_16x16x32_bf16(af[i], bfr[j], acc[i][j], 0, 0, 0);
    }
    __syncthreads();
  }

  if (MODE == 0) {
    __hip_bfloat16* C = (__hip_bfloat16*)Cout;
#pragma unroll
    for (int j = 0; j < 4; ++j) {
      int n = nt * 128 + (nw + j) * 16 + lrow;
      float bn = (n < Nreal) ? bias[n] : 0.f;
      int kt = n >> 6, kq = (n >> 5) & 1, lc2 = (n >> 3) & 3, j2 = n & 7;
#pragma unroll
      for (int i = 0; i < 4; ++i) {
        int mi = mw + i;
        size_t base = ((((size_t)mt * outKT + kt) * 16) + mi * 2 + kq) * 512
                      + (size_t)(lch * 4) * 8 + (size_t)lc2 * 128 + j2;
#pragma unroll
        for (int r = 0; r < 4; ++r)
          C[base + r * 8] = __float2bfloat16(fmaxf(acc[i][j][r] + bn, 0.f));
      }
    }
  } else {
    __half* P = (__half*)Cout + (size_t)blockIdx.z * 4096 * 1024;
#pragma unroll
    for (int j = 0; j < 4; ++j) {
      int n = nt * 128 + (nw + j) * 16 + lrow;
#pragma unroll
      for (int i = 0; i < 4; ++i)
#pragma unroll
        for (int r = 0; r < 4; ++r) {
          int m = mt * 128 + (mw + i) * 16 + lch * 4 + r;
          P[(size_t)m * Nn + n] = __float2half(acc[i][j][r]);
        }
    }
  }
}

// == final: relu(P0+P1+P2+P3+b2) @ W3 + b3 -> fp32 out (reduce fused) =======

__global__ __launch_bounds__(256) void gemm3_fused(
    const __half* __restrict__ P,     // [4][4096][1024] fp16
    const float* __restrict__ b2v,    // lb2 [1024]
    const float* __restrict__ W3,     // lW3 [1024,9]
    const float* __restrict__ b3v,    // lb3 [9]
    float* __restrict__ out)          // [4096,9]
{
  __shared__ float sW3[9 * 1024];
  int tid = threadIdx.x;
  for (int i = tid; i < 9216; i += 256) { int k = i / 9, j = i - 9 * k; sW3[j * 1024 + k] = W3[i]; }
  __syncthreads();
  int row = blockIdx.x * 4 + (tid >> 6);
  int lane = tid & 63;
  const __half* p0 = P + (size_t)row * 1024;
  const size_t S = (size_t)4096 * 1024;
  float acc[9] = {0, 0, 0, 0, 0, 0, 0, 0, 0};
  for (int t = 0; t < 16; ++t) {
    int k = lane + 64 * t;
    float c = __half2float(p0[k]) + __half2float(p0[k + S])
            + __half2float(p0[k + 2 * S]) + __half2float(p0[k + 3 * S]) + b2v[k];
    c = fmaxf(c, 0.f);
#pragma unroll
    for (int j = 0; j < 9; ++j) acc[j] += c * sW3[j * 1024 + k];
  }
#pragma unroll
  for (int j = 0; j < 9; ++j) {
    float v = acc[j];
    v += __shfl_down(v, 32, 64);
    v += __shfl_down(v, 16, 64);
    v += __shfl_down(v, 8, 64);
    v += __shfl_down(v, 4, 64);
    v += __shfl_down(v, 2, 64);
    v += __shfl_down(v, 1, 64);
    if (lane == 0) out[(size_t)row * 9 + j] = v + b3v[j];
  }
}

// ============================= launch =======================================

extern "C" void kernel_launch(void* const* d_in, const int* in_sizes, int n_in,
                              void* d_out, int out_size, void* d_ws, size_t ws_size,
                              hipStream_t stream)
{
  const float* x   = (const float*)d_in[0];
  const int*   ei  = (const int*)d_in[1];
  const float* W1  = (const float*)d_in[3];
  const float* a1s = (const float*)d_in[4];
  const float* a1d = (const float*)d_in[5];
  const float* b1  = (const float*)d_in[6];
  const float* W2  = (const float*)d_in[7];
  const float* a2s = (const float*)d_in[8];
  const float* a2d = (const float*)d_in[9];
  const float* b2  = (const float*)d_in[10];
  const float* W3  = (const float*)d_in[11];
  const float* a3s = (const float*)d_in[12];
  const float* a3d = (const float*)d_in[13];
  const float* b3  = (const float*)d_in[14];
  const float* lW1 = (const float*)d_in[15];
  const float* lb1 = (const float*)d_in[16];
  const float* lW2 = (const float*)d_in[17];
  const float* lb2 = (const float*)d_in[18];
  const float* lW3 = (const float*)d_in[19];
  const float* lb3 = (const float*)d_in[20];

  const int E = 4096 * 39 * 8;
  const int* esrc = ei;
  const int* edst = ei + E;

  // ws (bf16 elems): fA 13.6M | W1T 17.0M | C1 21.0M | W2T 5.2M  (~114 MB)
  short* fA  = (short*)d_ws;                       // tiled [4096,3328] KT=52
  short* W1T = fA  + (size_t)4096 * 3328;          // tiled [5120,3328] KT=52
  short* C1  = W1T + (size_t)5120 * 3328;          // tiled [4096,5120] KT=80
  short* W2T = C1  + (size_t)4096 * 5120;          // tiled [1024,5120] KT=80
  __half* P  = (__half*)d_ws;                      // 4x[4096,1024] fp16 (33.5MB), aliases fA+W1T (dead)

  conv_all<<<5440, 256, 0, stream>>>(lW1, lW2, W1T, W2T);
  gnn_block<<<4096, 128, 0, stream>>>(x, esrc, edst,
                                      W1, a1s, a1d, b1, W2, a2s, a2d, b2, W3, a3s, a3d, b3,
                                      (__hip_bfloat16*)fA);
  gemm_tiled<0><<<dim3(40, 32, 1), 256, 0, stream>>>(fA, W1T, lb1, 5000, C1, 5120, 52, 52, 80);
  gemm_tiled<1><<<dim3(8, 32, 4), 256, 0, stream>>>(C1, W2T, nullptr, 1024, P, 1024, 80, 20, 0);
  gemm3_fused<<<1024, 256, 0, stream>>>(P, lb2, lW3, lb3, (float*)d_out);
}